// Round 1
// baseline (161.055 us; speedup 1.0000x reference)
//
#include <hip/hip_runtime.h>
#include <math.h>

#define LAYERS  8
#define FEAT    3072
#define NCLASS  10
#define DIM     4096

typedef float v2f __attribute__((ext_vector_type(2)));
typedef float v4f __attribute__((ext_vector_type(4)));

// prefix-xor (inverse Gray) helpers; compile-time under unroll
__device__ __forceinline__ int px6c(int r){ int u = r ^ (r>>1); u ^= u>>2; u ^= u>>4; return u & 63; }
__device__ __forceinline__ int px5c(int r){ int u = r ^ (r>>1); u ^= u>>2; u ^= u>>4; return u & 31; }

__device__ __forceinline__ float getc16(const v2f v[16], int u){ return (u&1)? v[u>>1].y : v[u>>1].x; }
__device__ __forceinline__ void  setc16(v2f v[16], int u, float x){ if(u&1) v[u>>1].y = x; else v[u>>1].x = x; }

__device__ __forceinline__ float bpermf(int addr, float x){
    return __int_as_float(__builtin_amdgcn_ds_bpermute(addr, __float_as_int(x)));
}
// lane ^ 1 exchange via DPP quad_perm [1,0,3,2] (VALU, no LDS traffic)
__device__ __forceinline__ float dppx1(float x){
    return __int_as_float(__builtin_amdgcn_update_dpp(0, __float_as_int(x), 0xB1, 0xF, 0xF, true));
}

// 5 register-qubit butterflies (packed v2f); reg bit p uses cl[off-p]/sl[off-p]
__device__ __forceinline__ void butterflies5(v2f v[16],
                                             const float* __restrict__ cl,
                                             const float* __restrict__ sl,
                                             int off){
    {   // bit 0 = v2f component pair
        const float c = cl[off], s = sl[off];
        const v2f c2 = {c,c}, ms = {-s, s};
#pragma unroll
        for (int i=0;i<16;++i){ v2f a=v[i]; v2f sw={a.y,a.x}; v[i] = a*c2 + sw*ms; }
    }
#pragma unroll
    for (int p=1;p<5;++p){
        const float c = cl[off-p], s = sl[off-p];
        const v2f c2={c,c}, s2={s,s};
#pragma unroll
        for (int i0=0;i0<16;++i0){
            if (i0 & (1<<(p-1))) continue;
            const int i1 = i0 | (1<<(p-1));
            v2f a=v[i0], e=v[i1];
            v[i0] = a*c2 - e*s2;
            v[i1] = a*s2 + e*c2;
        }
    }
}

// 2 waves per state. Layouts:
//  L_B: thread (w,l) reg r  holds q[w<<11 | l<<5 | r ]  (r = j4..0)
//  L_A: thread (w,l) reg r' holds q[w<<11 | r'<<6 | l ]  (r' = j10..6)
// LDS swizzle (global rule, all patterns conflict-free):
//  phys = row*32 + (col ^ ((row&7)<<2)),  row = j>>5, col = j&31
__global__ __launch_bounds__(128, 4)
void qnn_kernel(const float* __restrict__ x,
                const float* __restrict__ ang,
                const float* __restrict__ W,
                const float* __restrict__ bias,
                float* __restrict__ out)
{
    __shared__ __attribute__((aligned(16))) float lds[4096];
    __shared__ float cst[96], snt[96], nrm[2], redc[NCLASS];

    const int t = threadIdx.x;       // 0..127
    const int w = t >> 6;            // wave = j11
    const int l = t & 63;            // lane = j10..5 (L_B) / j5..0 (L_A)
    const int b = blockIdx.x;

    if (t < 96){ float a = ang[t]; cst[t] = cosf(a); snt[t] = sinf(a); }
    __syncthreads();

    // ---- load psi0 in L_B: 32 consecutive floats per thread ----
    v2f v[16];
    {
        const float* xb = x + (size_t)b * FEAT;
        const int base = 2048*w + 32*l;
        if (base < FEAT){
#pragma unroll
            for (int i=0;i<8;++i){
                v4f q = *(const v4f*)(xb + base + 4*i);
                v[2*i]   = (v2f){q.x, q.y};
                v[2*i+1] = (v2f){q.z, q.w};
            }
        } else {
#pragma unroll
            for (int i=0;i<16;++i) v[i] = (v2f){0.f, 0.f};
        }
    }
    // ---- ||x||^2 partial (normalization deferred; circuit linear) ----
    {
        v2f s2 = {0.f,0.f};
#pragma unroll
        for (int i=0;i<16;++i) s2 += v[i]*v[i];
        float ss = s2.x + s2.y;
#pragma unroll
        for (int o=1;o<64;o<<=1) ss += __shfl_xor(ss, o, 64);
        if (l==0) nrm[w] = ss;
    }

    // ---- per-lane constants ----
    const int px = px6c(l);
    const int A0 = 4*px;             // bpermute byte addrs (Gray lane-field)
    const int A1 = 4*(px^63);
    const int AW = w ? A1 : A0;      // O4 single address
    const int wq = 2048*w;
    int wAf[8], rBf[4], rBfw[4];
#pragma unroll
    for (int i=0;i<8;++i) wAf[i] = 32*l + 4*(i ^ (l&7));      // quad bases, row=w*64+l
    {
        const int l5 = l>>5;
#pragma unroll
        for (int g=0;g<4;++g){
            rBf[g]  = 32*l5 + (((l&31) ^ (l5<<2)) ^ (g<<3));  // strided bases, g = r&3
            rBfw[g] = rBf[g] + wq;
        }
    }

#pragma unroll 1
    for (int p=0;p<4;++p){
        // =============== even layer 2p (L_B -> L_A) ===============
        {
            const float* cl = cst + 24*p;
            const float* sl = snt + 24*p;
            // E1: bits 4..0 (angles 11..7) + bit5 via lane^1 DPP (angle 6)
            butterflies5(v, cl, sl, 11);
            {
                const float c = cl[6], s = sl[6];
                const float sg = (l&1)? s : -s;
                const v2f c2={c,c}, sg2={sg,sg};
#pragma unroll
                for (int k=0;k<16;++k){
                    v2f pa = { dppx1(v[k].x), dppx1(v[k].y) };
                    v[k] = v[k]*c2 + pa*sg2;
                }
            }
            // E2: rotating transpose L_B -> L_A, folds bit11 rotation (angle 0)
            __syncthreads();
#pragma unroll
            for (int i=0;i<8;++i){
                v4f q = { v[2*i].x, v[2*i].y, v[2*i+1].x, v[2*i+1].y };
                *(v4f*)&lds[wAf[i] + wq] = q;                 // b128 rows, conflict-free
            }
            __syncthreads();
            {
                const float c0 = cl[0], s0 = sl[0];
                const float ca = w ? s0 : c0;
                const float cb = w ? c0 : -s0;
#pragma unroll
                for (int h=0;h<2;++h){                        // halves: limit reg pressure
                    float t0[16], t1[16];
#pragma unroll
                    for (int q=0;q<16;++q){
                        const int r = 16*h + q;
                        t0[q] = lds[rBf[r&3] + 64*r];          // wave-half 0
                        t1[q] = lds[rBf[r&3] + 64*r + 2048];   // wave-half 1
                    }
#pragma unroll
                    for (int q=0;q<16;++q)
                        setc16(v, 16*h+q, ca*t0[q] + cb*t1[q]);
                }
            }
            // E3: bits 10..6 (angles 5..1)
            butterflies5(v, cl, sl, 5);
            // E4: Gray in L_A: dest reg = gray5(r')^ (w<<4); dest lane = gray6(l)^((r'&1)<<5)
            {
                float n[32];
                if (w==0){
#pragma unroll
                    for (int dr=0;dr<32;++dr){
                        const int sr = px5c(dr);
                        n[dr] = bpermf((sr&1)? A1 : A0, getc16(v, sr));
                    }
                } else {
#pragma unroll
                    for (int dr=0;dr<32;++dr){
                        const int sr = px5c(dr) ^ 31;
                        n[dr] = bpermf((sr&1)? A1 : A0, getc16(v, sr));
                    }
                }
#pragma unroll
                for (int dr=0;dr<32;++dr) setc16(v, dr, n[dr]);
            }
        }
        // =============== odd layer 2p+1 (L_A -> L_B) ===============
        {
            const float* cl = cst + 24*p + 12;
            const float* sl = snt + 24*p + 12;
            // O1: bits 10..6 (angles 5..1)
            butterflies5(v, cl, sl, 5);
            // O2: rotating transpose L_A -> L_B, folds bit11 rotation (angle 0)
            __syncthreads();
#pragma unroll
            for (int r=0;r<32;++r) lds[rBfw[r&3] + 64*r] = getc16(v, r);  // b32, 2-way free
            __syncthreads();
            {
                const float c0 = cl[0], s0 = sl[0];
                const float ca = w ? s0 : c0;
                const float cb = w ? c0 : -s0;
#pragma unroll
                for (int h=0;h<2;++h){
                    float t0[16], t1[16];
#pragma unroll
                    for (int i=0;i<4;++i){
                        const int ii = 4*h + i;
                        v4f a  = *(const v4f*)&lds[wAf[ii]];
                        v4f bq = *(const v4f*)&lds[wAf[ii] + 2048];
                        t0[4*i]=a.x;  t0[4*i+1]=a.y;  t0[4*i+2]=a.z;  t0[4*i+3]=a.w;
                        t1[4*i]=bq.x; t1[4*i+1]=bq.y; t1[4*i+2]=bq.z; t1[4*i+3]=bq.w;
                    }
#pragma unroll
                    for (int q=0;q<16;++q)
                        setc16(v, 16*h+q, ca*t0[q] + cb*t1[q]);
                }
            }
            // O3: bits 4..0 (angles 11..7) + bit5 (angle 6)
            butterflies5(v, cl, sl, 11);
            {
                const float c = cl[6], s = sl[6];
                const float sg = (l&1)? s : -s;
                const v2f c2={c,c}, sg2={sg,sg};
#pragma unroll
                for (int k=0;k<16;++k){
                    v2f pa = { dppx1(v[k].x), dppx1(v[k].y) };
                    v[k] = v[k]*c2 + pa*sg2;
                }
            }
            // O4: Gray in L_B: dest lane = gray6(l)^(w<<5); dest reg = gray5(r)^((l&1)<<4)
            {
                float ug[32], n[32];
                const bool po = (l & 1);
#pragma unroll
                for (int k=0;k<32;++k) ug[k] = po ? getc16(v, k^31) : getc16(v, k);
#pragma unroll
                for (int dr=0;dr<32;++dr) n[dr] = bpermf(AW, ug[px5c(dr)]);
#pragma unroll
                for (int dr=0;dr<32;++dr) setc16(v, dr, n[dr]);
            }
        }
    }

    // ---- epilogue: probs = psi^2 (L_B, contiguous 32/thread), dot with W ----
    float acc[NCLASS];
#pragma unroll
    for (int c=0;c<NCLASS;++c) acc[c] = 0.f;
    {
        const float* wp0 = W + 2048*w + 32*l;
#pragma unroll 1
        for (int k=0;k<8;++k){
            v2f a = v[2*k], bb = v[2*k+1];
            v4f pq = { a.x*a.x, a.y*a.y, bb.x*bb.x, bb.y*bb.y };
            const float* wp = wp0 + 4*k;
#pragma unroll
            for (int c=0;c<NCLASS;++c){
                v4f w4 = *(const v4f*)(wp + c*DIM);            // dwordx4, L2-resident
                acc[c] += pq.x*w4.x + pq.y*w4.y + pq.z*w4.z + pq.w*w4.w;
            }
        }
    }
#pragma unroll
    for (int c=0;c<NCLASS;++c){
        float a2 = acc[c];
#pragma unroll
        for (int o=1;o<64;o<<=1) a2 += __shfl_xor(a2, o, 64);
        acc[c] = a2;
    }
    if (w==1 && l==0){
#pragma unroll
        for (int c=0;c<NCLASS;++c) redc[c] = acc[c];
    }
    __syncthreads();
    if (w==0 && l==0){
        const float invn2 = 1.f / (nrm[0] + nrm[1]);
#pragma unroll
        for (int c=0;c<NCLASS;++c)
            out[b*NCLASS + c] = fmaf(acc[c] + redc[c], invn2, bias[c]);
    }
}

extern "C" void kernel_launch(void* const* d_in, const int* in_sizes, int n_in,
                              void* d_out, int out_size, void* d_ws, size_t ws_size,
                              hipStream_t stream) {
    const float* x    = (const float*)d_in[0];
    const float* ang  = (const float*)d_in[1];
    const float* W    = (const float*)d_in[2];
    const float* bias = (const float*)d_in[3];
    float* out = (float*)d_out;
    const int batch = in_sizes[0] / FEAT;   // 2048
    qnn_kernel<<<batch, 128, 0, stream>>>(x, ang, W, bias, out);
}

// Round 2
// 122.221 us; speedup vs baseline: 1.3177x; 1.3177x over previous
//
#include <hip/hip_runtime.h>
#include <math.h>

#define LAYERS  8
#define FEAT    3072
#define NCLASS  10
#define DIM     4096
#define ST      68            // padded LDS row stride (floats); ST%4==0 -> b128-able, ST%32==4
#define SBF     (ST * 64)     // per-stream LDS float offset (4352 floats = 17408 B)

typedef float v2f __attribute__((ext_vector_type(2)));
typedef float v4f __attribute__((ext_vector_type(4)));

// prefix-xor (inverse Gray) of 6-bit value; compile-time under unroll
__device__ __forceinline__ int px6c(int r) {
    int u = r ^ (r >> 1); u ^= u >> 2; u ^= u >> 4; return u & 63;
}
__device__ __forceinline__ int gray6(int r) { return (r ^ (r >> 1)) & 63; }

__device__ __forceinline__ float getc(const v2f v[32], int u) {
    return (u & 1) ? v[u >> 1].y : v[u >> 1].x;
}
__device__ __forceinline__ void setc(v2f v[32], int u, float x) {
    if (u & 1) v[u >> 1].y = x; else v[u >> 1].x = x;
}
__device__ __forceinline__ float bpermf(int addr, float x) {
    return __int_as_float(__builtin_amdgcn_ds_bpermute(addr, __float_as_int(x)));
}

// plain 6 register-qubit butterflies (packed v2f); reg bit p uses cl[off-p]/sl[off-p]
__device__ __forceinline__ void butterflies6(v2f v[32],
                                             const float* __restrict__ cl,
                                             const float* __restrict__ sl,
                                             int off) {
    {
        const float c = cl[off], s = sl[off];
        const v2f c2 = {c, c};
        const v2f ms = {-s, s};
#pragma unroll
        for (int i = 0; i < 32; ++i) {
            v2f a = v[i];
            v2f sw = {a.y, a.x};
            v[i] = a * c2 + sw * ms;   // (c*x - s*y, s*x + c*y)
        }
    }
#pragma unroll
    for (int p = 1; p < 6; ++p) {
        const float c = cl[off - p], s = sl[off - p];
        const v2f c2 = {c, c};
        const v2f s2 = {s, s};
#pragma unroll
        for (int i0 = 0; i0 < 32; ++i0) {
            if (i0 & (1 << (p - 1))) continue;
            const int i1 = i0 | (1 << (p - 1));
            v2f a = v[i0], e = v[i1];
            v[i0] = a * c2 - e * s2;
            v[i1] = a * s2 + e * c2;
        }
    }
}

// A-phase CONJUGATED by the deferred GrayA (verified rounds 7/8 of prior session).
__device__ __forceinline__ void butterflies6_renamed(v2f v[32],
                                                     const float* __restrict__ cl,
                                                     const float* __restrict__ sl,
                                                     float psgn) {
    {
        const float c = cl[11], s = sl[11];
        const v2f c2 = {c, c};
        const v2f msA = {-s, s};
        const v2f msB = {s, -s};
#pragma unroll
        for (int k = 0; k < 32; ++k) {
            v2f a = v[k];
            v2f sw = {a.y, a.x};
            v[k] = a * c2 + sw * ((k & 1) ? msB : msA);
        }
    }
#pragma unroll
    for (int b = 1; b < 5; ++b) {
        const float c = cl[11 - b], s = sl[11 - b];
        const v2f c2 = {c, c};
#pragma unroll
        for (int m = 0; m < 32; ++m) {
            if (m & (1 << (b - 1))) continue;
            const int part = m ^ ((1 << b) - 1);
            const float sg = (m & (1 << b)) ? -s : s;
            const v2f sg2 = {sg, sg};
            const v2f A = v[m], E = v[part];
            const v2f Esw = {E.y, E.x};
            const v2f Asw = {A.y, A.x};
            v[m]    = A * c2 - Esw * sg2;
            v[part] = Asw * sg2 + E * c2;
        }
    }
    {
        const float c = cl[6];
        const float snl = psgn * sl[6];
        const v2f c2 = {c, c};
        const v2f sg2 = {snl, snl};
#pragma unroll
        for (int m = 0; m < 16; ++m) {
            const int part = m ^ 31;
            const v2f A = v[m], E = v[part];
            const v2f Esw = {E.y, E.x};
            const v2f Asw = {A.y, A.x};
            v[m]    = A * c2 - Esw * sg2;
            v[part] = Asw * sg2 + E * c2;
        }
    }
}

// One wave per block; each wave carries TWO batch states (ILP latency hiding,
// zero barriers, in-order DS). LDS: two independent 17.4KB regions.
__global__ __launch_bounds__(64, 1)
void qnn_kernel(const float* __restrict__ x,
                const float* __restrict__ ang,
                const float* __restrict__ W,
                const float* __restrict__ bias,
                float* __restrict__ out,
                int batch)
{
    __shared__ __attribute__((aligned(16))) float lds[2 * SBF];   // 34816 B
    __shared__ float cst[96], snt[96];

    const int t = threadIdx.x;          // 0..63, single wave per block
    const int b = blockIdx.x;
    const int b0 = 2 * b, b1 = 2 * b + 1;
    const bool has1 = (b1 < batch);

    // ---- trig tables (96 angles); single wave, in-order DS -> no barrier ----
    {
        float a0 = ang[t];
        cst[t] = cosf(a0);
        snt[t] = sinf(a0);
        if (t < 32) {
            float a1 = ang[64 + t];
            cst[64 + t] = cosf(a1);
            snt[64 + t] = sinf(a1);
        }
    }

    // ---- load psi0 for both streams in B layout: v[r] = psi[64r + t] ----
    v2f v0[32], v1[32];
    {
        const float* xb = x + (size_t)b0 * FEAT;
#pragma unroll
        for (int r = 0; r < 64; ++r) {
            if (r < FEAT / 64) setc(v0, r, xb[64 * r + t]);
            else               setc(v0, r, 0.f);
        }
    }
    if (has1) {
        const float* xb = x + (size_t)b1 * FEAT;
#pragma unroll
        for (int r = 0; r < 64; ++r) {
            if (r < FEAT / 64) setc(v1, r, xb[64 * r + t]);
            else               setc(v1, r, 0.f);
        }
    } else {
#pragma unroll
        for (int i = 0; i < 32; ++i) v1[i] = (v2f){0.f, 0.f};
    }

    // ---- ||x||^2 per stream (normalization deferred: circuit is linear) ----
    float invn0, invn1;
    {
        v2f s2 = {0.f, 0.f};
#pragma unroll
        for (int i = 0; i < 32; ++i) s2 += v0[i] * v0[i];
        float ss = s2.x + s2.y;
#pragma unroll
        for (int o = 1; o < 64; o <<= 1) ss += __shfl_xor(ss, o, 64);
        invn0 = 1.0f / ss;
    }
    {
        v2f s2 = {0.f, 0.f};
#pragma unroll
        for (int i = 0; i < 32; ++i) s2 += v1[i] * v1[i];
        float ss = s2.x + s2.y;
#pragma unroll
        for (int o = 1; o < 64; o <<= 1) ss += __shfl_xor(ss, o, 64);
        invn1 = 1.0f / ss;           // inf when stream 1 absent; never stored
    }

    // ---- anti-lock-step skew keyed on SIMD id (1 wave/SIMD now) ----
    {
        const int slot = __builtin_amdgcn_s_getreg(4 | (4 << 6) | (1 << 11)) & 3;  // HW_ID.SIMD_ID
#pragma unroll 1
        for (int i = 0; i < slot; ++i) __builtin_amdgcn_s_sleep(12);   // 12*64 cyc
    }

    // ---- per-lane constants ----
    int px = t ^ (t >> 1); px ^= px >> 2; px ^= px >> 4; px &= 63;  // px6(t)
    const int A0 = 4 * px;                    // bpermute byte addrs (GrayB)
    const int A1 = 4 * (px ^ 63);
    const int u0 = t & 1;
    const float psgn = u0 ? -1.f : 1.f;       // parity sign for renamed b=5
    const int gtl = gray6(t);
    const int bp  = gtl + 32 * ST * u0;       // folded-GrayA store bases
    const int bm  = gtl - 32 * ST * u0;

    // ---- phase helpers (SB is compile-time under unroll; DS offsets fold) ----
    auto storeRows = [&](const v2f* vv, const int SB) {
#pragma unroll
        for (int i = 0; i < 16; ++i) {                // b128 rows, floor-free
            v4f q = {vv[2 * i].x, vv[2 * i].y, vv[2 * i + 1].x, vv[2 * i + 1].y};
            *(v4f*)(lds + SB + ST * t + 4 * i) = q;
        }
    };
    auto readCols = [&](v2f* vv, const int SB) {
#pragma unroll
        for (int u = 0; u < 64; ++u)                  // b32 cols, 2-way free
            setc(vv, u, lds[SB + t + ST * u]);
    };
    auto foldedStore = [&](const v2f* vv, const int SB) {
        // transpose A->B with GrayA folded into store addresses
#pragma unroll
        for (int s = 0; s < 64; ++s) {
            const int g = gray6(s);                       // compile-time
            lds[SB + ((g & 32) ? bm : bp) + ST * g] = getc(vv, s);
        }
    };
    auto rowRead = [&](v2f* vv, const int SB) {
#pragma unroll
        for (int i = 0; i < 16; ++i) {                // b128 rows
            v4f q = *(const v4f*)(lds + SB + ST * t + 4 * i);
            vv[2 * i]     = (v2f){q.x, q.y};
            vv[2 * i + 1] = (v2f){q.z, q.w};
        }
    };
    auto grayB = [&](v2f* vv) {
        // GrayB (eager): new[r] = bperm(parity(src)?A1:A0, old[px6(r)])
        float n[64];
#pragma unroll
        for (int r = 0; r < 64; ++r) {
            const int srcr = px6c(r);                 // compile-time
            n[r] = bpermf((srcr & 1) ? A1 : A0, getc(vv, srcr));
        }
#pragma unroll
        for (int r = 0; r < 64; ++r) setc(vv, r, n[r]);
    };

    // ---- layer 0 (even, clean): B-phase, transpose B->A, A-phase ----
    {
        const float* cl = cst;
        const float* sl = snt;
        butterflies6(v0, cl, sl, 5);                  // qubits 5..0 (reg = hi bits)
        butterflies6(v1, cl, sl, 5);
        storeRows(v0, 0);  storeRows(v1, SBF);
        readCols(v0, 0);   readCols(v1, SBF);
        butterflies6(v0, cl, sl, 11);                 // qubits 11..6 (reg = lo bits)
        butterflies6(v1, cl, sl, 11);
        // GrayA(0): deferred into layer 1
    }

#pragma unroll 1
    for (int p = 0; p < 4; ++p) {
        // ======== odd layer 2p+1: renamed A-phase, folded transpose, B-phase ========
        {
            const float* cl = cst + (2 * p + 1) * 12;
            const float* sl = snt + (2 * p + 1) * 12;

            butterflies6_renamed(v0, cl, sl, psgn);
            butterflies6_renamed(v1, cl, sl, psgn);
            foldedStore(v0, 0);  foldedStore(v1, SBF);
            rowRead(v0, 0);      rowRead(v1, SBF);
            butterflies6(v0, cl, sl, 5);              // qubits 5..0
            butterflies6(v1, cl, sl, 5);

            if (p < 3) {
                grayB(v0);
                grayB(v1);
            }
            // p == 3 (layer 7): final Gray folds into the epilogue scatter
        }

        if (p == 3) break;

        // ======== even layer 2p+2 (clean): B-phase, transpose B->A, A-phase ========
        {
            const float* cl = cst + (2 * p + 2) * 12;
            const float* sl = snt + (2 * p + 2) * 12;

            butterflies6(v0, cl, sl, 5);
            butterflies6(v1, cl, sl, 5);
            storeRows(v0, 0);  storeRows(v1, SBF);
            readCols(v0, 0);   readCols(v1, SBF);
            butterflies6(v0, cl, sl, 11);
            butterflies6(v1, cl, sl, 11);
            // GrayA: deferred into next odd layer
        }
    }

    // ---- epilogue (B layout, Gray(7) folded): q[g(j)] = psi[j]^2,
    //      j = 64r + t, g(j) = 64*gray6(r) + (gray6(t) ^ 32*(r&1)) ----
#pragma unroll
    for (int i = 0; i < 32; ++i) {
        const int g0 = 64 * gray6(2 * i);
        const int g1 = 64 * (gray6(2 * i) ^ 1);
        lds[g0 + gtl]        = v0[i].x * v0[i].x;     // bank = gtl&31: 2-way, free
        lds[g1 + (gtl ^ 32)] = v0[i].y * v0[i].y;
        lds[SBF + g0 + gtl]        = v1[i].x * v1[i].x;
        lds[SBF + g1 + (gtl ^ 32)] = v1[i].y * v1[i].y;
    }

    float acc0[NCLASS], acc1[NCLASS];
#pragma unroll
    for (int c = 0; c < NCLASS; ++c) { acc0[c] = 0.f; acc1[c] = 0.f; }

#pragma unroll 1
    for (int k = 0; k < 16; ++k) {
        const v4f qa = *(const v4f*)(lds + 4 * t + 256 * k);         // b128, floor-free
        const v4f qb = *(const v4f*)(lds + SBF + 4 * t + 256 * k);
        const float* wp = W + 4 * t + 256 * k;
#pragma unroll
        for (int c = 0; c < NCLASS; ++c) {
            const v4f w4 = *(const v4f*)(wp + c * DIM);              // shared by both streams
            acc0[c] += qa.x * w4.x + qa.y * w4.y + qa.z * w4.z + qa.w * w4.w;
            acc1[c] += qb.x * w4.x + qb.y * w4.y + qb.z * w4.z + qb.w * w4.w;
        }
    }

#pragma unroll
    for (int c = 0; c < NCLASS; ++c) {
        float a0 = acc0[c], a1 = acc1[c];
#pragma unroll
        for (int o = 1; o < 64; o <<= 1) {
            a0 += __shfl_xor(a0, o, 64);
            a1 += __shfl_xor(a1, o, 64);
        }
        if (t == 0) {
            out[b0 * NCLASS + c] = fmaf(a0, invn0, bias[c]);
            if (has1) out[b1 * NCLASS + c] = fmaf(a1, invn1, bias[c]);
        }
    }
}

extern "C" void kernel_launch(void* const* d_in, const int* in_sizes, int n_in,
                              void* d_out, int out_size, void* d_ws, size_t ws_size,
                              hipStream_t stream) {
    const float* x    = (const float*)d_in[0];
    const float* ang  = (const float*)d_in[1];
    const float* W    = (const float*)d_in[2];
    const float* bias = (const float*)d_in[3];
    float* out = (float*)d_out;
    const int batch = in_sizes[0] / FEAT;   // 2048
    const int blocks = (batch + 1) / 2;     // 1024: two states per wave
    qnn_kernel<<<blocks, 64, 0, stream>>>(x, ang, W, bias, out, batch);
}